// Round 1
// baseline (205.316 us; speedup 1.0000x reference)
//
#include <hip/hip_runtime.h>

#define NSAMP 2048
#define DIM 1024
#define NCLS 224
#define PERCLS 224
#define TOP_S 8
#define BOT_S 16

struct Ws {
  int cls[NSAMP];
  int within[NSAMP];
  int order[NSAMP];
  int offsets[NCLS + 1];
  float ptop[NSAMP];
};

// ---------------- prep: cls/within + class-grouped sample order ----------------
__global__ void prep_kernel(const int* __restrict__ target, Ws* __restrict__ ws) {
  __shared__ int cnt[NCLS];
  __shared__ int cur[NCLS];
  int tid = threadIdx.x;
  for (int c = tid; c < NCLS; c += blockDim.x) cnt[c] = 0;
  __syncthreads();
  for (int n = tid; n < NSAMP; n += blockDim.x) {
    int t = target[n];
    int c = t / PERCLS;
    ws->cls[n] = c;
    ws->within[n] = t - c * PERCLS;
    atomicAdd(&cnt[c], 1);
  }
  __syncthreads();
  if (tid == 0) {
    int run = 0;
    for (int c = 0; c < NCLS; ++c) {
      cur[c] = run;
      ws->offsets[c] = run;
      run += cnt[c];
    }
    ws->offsets[NCLS] = run;
  }
  __syncthreads();
  for (int n = tid; n < NSAMP; n += blockDim.x) {
    int t = target[n];
    int c = t / PERCLS;
    int pos = atomicAdd(&cur[c], 1);
    ws->order[pos] = n;
  }
}

// ---------------- top: dense 2048x224 logits + softmax, keep target prob ------
__global__ __launch_bounds__(256) void top_kernel(const float* __restrict__ x,
                                                  const float* __restrict__ tw,
                                                  const float* __restrict__ tb,
                                                  Ws* __restrict__ ws) {
  __shared__ float xs[TOP_S][DIM];     // 32 KB
  __shared__ float lg[TOP_S][NCLS];    // 7 KB
  const int tid = threadIdx.x;
  const int n0 = blockIdx.x * TOP_S;

  // stage x rows (coalesced float4)
  const float4* xg = (const float4*)x;
  float4* xsv = (float4*)&xs[0][0];
  for (int i = tid; i < TOP_S * (DIM / 4); i += 256) {
    int s = i >> 8;          // /256
    int f = i & 255;
    xsv[i] = xg[(size_t)(n0 + s) * (DIM / 4) + f];
  }
  __syncthreads();

  const int c = tid;
  if (c < NCLS) {
    float acc[TOP_S];
#pragma unroll
    for (int s = 0; s < TOP_S; ++s) acc[s] = 0.f;
    const float* W = tw + c;
    for (int d = 0; d < DIM; d += 8) {
      float w[8];
#pragma unroll
      for (int j = 0; j < 8; ++j) w[j] = W[(size_t)(d + j) * NCLS];
#pragma unroll
      for (int j = 0; j < 8; ++j) {
#pragma unroll
        for (int s = 0; s < TOP_S; ++s)
          acc[s] = fmaf(xs[s][d + j], w[j], acc[s]);
      }
    }
    float bias = tb[c];
#pragma unroll
    for (int s = 0; s < TOP_S; ++s) lg[s][c] = acc[s] + bias;
  }
  __syncthreads();

  // softmax: 4 waves x 2 samples
  const int wv = tid >> 6, lane = tid & 63;
  for (int s = wv * 2; s < wv * 2 + 2; ++s) {
    float v[4];
    float mx = -INFINITY;
#pragma unroll
    for (int j = 0; j < 4; ++j) {
      int p = lane + 64 * j;
      v[j] = (p < NCLS) ? lg[s][p] : -INFINITY;
      mx = fmaxf(mx, v[j]);
    }
#pragma unroll
    for (int m = 32; m >= 1; m >>= 1) mx = fmaxf(mx, __shfl_xor(mx, m));
    float sum = 0.f;
#pragma unroll
    for (int j = 0; j < 4; ++j) {
      int p = lane + 64 * j;
      if (p < NCLS) sum += expf(v[j] - mx);
    }
#pragma unroll
    for (int m = 32; m >= 1; m >>= 1) sum += __shfl_xor(sum, m);
    int n = n0 + s;
    int cl = ws->cls[n];
    float pt = expf(lg[s][cl] - mx) / sum;
    if (lane == 0) ws->ptop[n] = pt;
  }
}

// ---------------- bottom: per-class gathered GEMM + softmax + final product ---
__global__ __launch_bounds__(512) void bottom_kernel(const float* __restrict__ x,
                                                     const float* __restrict__ bw,
                                                     const float* __restrict__ bb,
                                                     const Ws* __restrict__ ws,
                                                     float* __restrict__ out) {
  __shared__ float xs[BOT_S][DIM];     // 64 KB
  __shared__ float red[BOT_S][NCLS];   // 14 KB (also holds final logits)
  const int c = blockIdx.x;
  const int start = ws->offsets[c];
  const int K = ws->offsets[c + 1] - start;
  if (K == 0) return;

  const int tid = threadIdx.x;
  const int half = tid >> 8;     // D-split: 0 -> [0,512), 1 -> [512,1024)
  const int p = tid & 255;
  const bool active = p < NCLS;
  const float* Wp = bw + (size_t)c * (DIM * PERCLS) + p;

  for (int chunk = 0; chunk < K; chunk += BOT_S) {
    const int S = min(BOT_S, K - chunk);
    __syncthreads();   // protect xs/red from previous iteration's readers

    // stage S sample rows of x (coalesced float4 within each row)
    for (int i = tid; i < S * (DIM / 4); i += 512) {
      int s = i >> 8;
      int f = i & 255;
      int n = ws->order[start + chunk + s];
      ((float4*)xs)[s * (DIM / 4) + f] = ((const float4*)x)[(size_t)n * (DIM / 4) + f];
    }
    __syncthreads();

    float acc[BOT_S];
#pragma unroll
    for (int s = 0; s < BOT_S; ++s) acc[s] = 0.f;
    if (active) {
      const int dbase = half * (DIM / 2);
      for (int d = dbase; d < dbase + DIM / 2; d += 8) {
        float w[8];
#pragma unroll
        for (int j = 0; j < 8; ++j) w[j] = Wp[(size_t)(d + j) * PERCLS];
#pragma unroll
        for (int j = 0; j < 8; ++j) {
#pragma unroll
          for (int s = 0; s < BOT_S; ++s)
            acc[s] = fmaf(xs[s][d + j], w[j], acc[s]);
        }
      }
    }

    // reduce the two D-halves, add bias -> logits in red[][]
    if (half == 1 && active) {
#pragma unroll
      for (int s = 0; s < BOT_S; ++s) red[s][p] = acc[s];
    }
    __syncthreads();
    if (half == 0 && active) {
      float bias = bb[(size_t)c * PERCLS + p];
#pragma unroll
      for (int s = 0; s < BOT_S; ++s) red[s][p] = acc[s] + red[s][p] + bias;
    }
    __syncthreads();

    // softmax: 8 waves x 2 samples
    const int wv = tid >> 6, lane = tid & 63;
    for (int s = wv * 2; s < wv * 2 + 2; ++s) {
      if (s >= S) continue;   // wave-uniform
      float v[4];
      float mx = -INFINITY;
#pragma unroll
      for (int j = 0; j < 4; ++j) {
        int pp = lane + 64 * j;
        v[j] = (pp < NCLS) ? red[s][pp] : -INFINITY;
        mx = fmaxf(mx, v[j]);
      }
#pragma unroll
      for (int m = 32; m >= 1; m >>= 1) mx = fmaxf(mx, __shfl_xor(mx, m));
      float sum = 0.f;
#pragma unroll
      for (int j = 0; j < 4; ++j) {
        int pp = lane + 64 * j;
        if (pp < NCLS) sum += expf(v[j] - mx);
      }
#pragma unroll
      for (int m = 32; m >= 1; m >>= 1) sum += __shfl_xor(sum, m);
      int n = ws->order[start + chunk + s];
      int wn = ws->within[n];
      float pb = expf(red[s][wn] - mx) / sum;
      if (lane == 0) out[n] = ws->ptop[n] * pb;
    }
  }
}

extern "C" void kernel_launch(void* const* d_in, const int* in_sizes, int n_in,
                              void* d_out, int out_size, void* d_ws, size_t ws_size,
                              hipStream_t stream) {
  const float* x  = (const float*)d_in[0];
  const int* tgt  = (const int*)d_in[1];
  const float* tw = (const float*)d_in[2];
  const float* tb = (const float*)d_in[3];
  const float* bw = (const float*)d_in[4];
  const float* bb = (const float*)d_in[5];
  float* out = (float*)d_out;
  Ws* ws = (Ws*)d_ws;

  prep_kernel<<<1, 256, 0, stream>>>(tgt, ws);
  top_kernel<<<NSAMP / TOP_S, 256, 0, stream>>>(x, tw, tb, ws);
  bottom_kernel<<<NCLS, 512, 0, stream>>>(x, bw, bb, ws, out);
}

// Round 2
// 114.632 us; speedup vs baseline: 1.7911x; 1.7911x over previous
//
#include <hip/hip_runtime.h>

#define NSAMP 2048
#define DIM 1024
#define NCLS 224
#define PERCLS 224
#define NSPLIT 4
#define DSL (DIM / NSPLIT)      // 256 per D-slice
#define CH 16                   // samples per chunk
#define TOPBLKS ((NSAMP / CH) * NSPLIT)   // 128*4 = 512
#define BOTBLKS (NCLS * NSPLIT)           // 224*4 = 896

struct Ws {
  int cls[NSAMP];
  int within[NSAMP];
  int order[NSAMP];
  int offsets[NCLS + 1];
  float top_part[NSPLIT][NSAMP][NCLS];
  float bot_part[NSPLIT][NSAMP][PERCLS];
};

// ---------------- prep: cls/within + class-grouped sample order ----------------
__global__ void prep_kernel(const int* __restrict__ target, Ws* __restrict__ ws) {
  __shared__ int cnt[NCLS];
  __shared__ int cur[NCLS];
  int tid = threadIdx.x;
  for (int c = tid; c < NCLS; c += blockDim.x) cnt[c] = 0;
  __syncthreads();
  for (int n = tid; n < NSAMP; n += blockDim.x) {
    int t = target[n];
    int c = t / PERCLS;
    ws->cls[n] = c;
    ws->within[n] = t - c * PERCLS;
    atomicAdd(&cnt[c], 1);
  }
  __syncthreads();
  if (tid == 0) {
    int run = 0;
    for (int c = 0; c < NCLS; ++c) {
      cur[c] = run;
      ws->offsets[c] = run;
      run += cnt[c];
    }
    ws->offsets[NCLS] = run;
  }
  __syncthreads();
  for (int n = tid; n < NSAMP; n += blockDim.x) {
    int t = target[n];
    int c = t / PERCLS;
    int pos = atomicAdd(&cur[c], 1);
    ws->order[pos] = n;
  }
}

// ---------------- partial: D-split partial logits for top AND bottom ----------
__global__ __launch_bounds__(256) void partial_kernel(const float* __restrict__ x,
                                                      const float* __restrict__ tw,
                                                      const float* __restrict__ bw,
                                                      Ws* __restrict__ ws) {
  __shared__ float xs[CH][DSL];    // 16 KB
  const int tid = threadIdx.x;
  const int bid = blockIdx.x;

  if (bid < TOPBLKS) {
    // ---- top branch: sample-chunk sc, d-slice dc ----
    const int sc = bid >> 2;
    const int dc = bid & 3;
    const int n0 = sc * CH;
    const int dbase = dc * DSL;

    for (int i = tid; i < CH * (DSL / 4); i += 256) {
      int s = i >> 6;
      int f = i & 63;
      ((float4*)xs)[i] = ((const float4*)(x + (size_t)(n0 + s) * DIM + dbase))[f];
    }
    __syncthreads();

    const int p = tid;
    if (p < NCLS) {
      float acc[CH];
#pragma unroll
      for (int s = 0; s < CH; ++s) acc[s] = 0.f;
      const float* W = tw + p;
      for (int d = 0; d < DSL; d += 8) {
        float w[8];
#pragma unroll
        for (int j = 0; j < 8; ++j) w[j] = W[(size_t)(dbase + d + j) * NCLS];
#pragma unroll
        for (int j = 0; j < 8; ++j) {
#pragma unroll
          for (int s = 0; s < CH; ++s)
            acc[s] = fmaf(xs[s][d + j], w[j], acc[s]);
        }
      }
#pragma unroll
      for (int s = 0; s < CH; ++s) ws->top_part[dc][n0 + s][p] = acc[s];
    }
  } else {
    // ---- bottom branch: class c, d-slice dc ----
    const int b = bid - TOPBLKS;
    const int c = b >> 2;
    const int dc = b & 3;
    const int start = ws->offsets[c];
    const int K = ws->offsets[c + 1] - start;
    if (K == 0) return;
    const int dbase = dc * DSL;
    const float* W = bw + (size_t)c * (DIM * PERCLS) + tid;

    for (int chunk = 0; chunk < K; chunk += CH) {
      const int S = min(CH, K - chunk);
      if (chunk) __syncthreads();
      for (int i = tid; i < S * (DSL / 4); i += 256) {
        int s = i >> 6;
        int f = i & 63;
        int n = ws->order[start + chunk + s];
        ((float4*)xs)[i] = ((const float4*)(x + (size_t)n * DIM + dbase))[f];
      }
      __syncthreads();

      float acc[CH];
#pragma unroll
      for (int s = 0; s < CH; ++s) acc[s] = 0.f;
      if (tid < PERCLS) {
        for (int d = 0; d < DSL; d += 8) {
          float w[8];
#pragma unroll
          for (int j = 0; j < 8; ++j) w[j] = W[(size_t)(dbase + d + j) * PERCLS];
#pragma unroll
          for (int j = 0; j < 8; ++j) {
#pragma unroll
            for (int s = 0; s < CH; ++s)
              acc[s] = fmaf(xs[s][d + j], w[j], acc[s]);
          }
        }
        for (int s = 0; s < S; ++s)
          ws->bot_part[dc][ws->order[start + chunk + s]][tid] = acc[s];
      }
    }
  }
}

// ---------------- final: reduce partials + both softmaxes + product -----------
__global__ __launch_bounds__(256) void final_kernel(const float* __restrict__ tb,
                                                    const float* __restrict__ bb,
                                                    const Ws* __restrict__ ws,
                                                    float* __restrict__ out) {
  __shared__ float lt[8][NCLS];   // 7 KB
  __shared__ float lb[8][NCLS];   // 7 KB
  const int tid = threadIdx.x;
  const int n0 = blockIdx.x * 8;
  const int p = tid;

  if (p < NCLS) {
    float tbias = tb[p];
#pragma unroll
    for (int s = 0; s < 8; ++s) {
      int n = n0 + s;
      int c = ws->cls[n];
      float t = tbias;
      float b = bb[(size_t)c * PERCLS + p];
#pragma unroll
      for (int dc = 0; dc < NSPLIT; ++dc) t += ws->top_part[dc][n][p];
#pragma unroll
      for (int dc = 0; dc < NSPLIT; ++dc) b += ws->bot_part[dc][n][p];
      lt[s][p] = t;
      lb[s][p] = b;
    }
  }
  __syncthreads();

  const int wv = tid >> 6, lane = tid & 63;
  for (int s = wv * 2; s < wv * 2 + 2; ++s) {
    const int n = n0 + s;
    // top softmax
    float v[4], mx = -INFINITY;
#pragma unroll
    for (int j = 0; j < 4; ++j) {
      int pp = lane + 64 * j;
      v[j] = (pp < NCLS) ? lt[s][pp] : -INFINITY;
      mx = fmaxf(mx, v[j]);
    }
#pragma unroll
    for (int m = 32; m >= 1; m >>= 1) mx = fmaxf(mx, __shfl_xor(mx, m));
    float sum = 0.f;
#pragma unroll
    for (int j = 0; j < 4; ++j) {
      int pp = lane + 64 * j;
      if (pp < NCLS) sum += expf(v[j] - mx);
    }
#pragma unroll
    for (int m = 32; m >= 1; m >>= 1) sum += __shfl_xor(sum, m);
    float pt = expf(lt[s][ws->cls[n]] - mx) / sum;

    // bottom softmax
    float mb = -INFINITY;
#pragma unroll
    for (int j = 0; j < 4; ++j) {
      int pp = lane + 64 * j;
      v[j] = (pp < NCLS) ? lb[s][pp] : -INFINITY;
      mb = fmaxf(mb, v[j]);
    }
#pragma unroll
    for (int m = 32; m >= 1; m >>= 1) mb = fmaxf(mb, __shfl_xor(mb, m));
    float sb = 0.f;
#pragma unroll
    for (int j = 0; j < 4; ++j) {
      int pp = lane + 64 * j;
      if (pp < NCLS) sb += expf(v[j] - mb);
    }
#pragma unroll
    for (int m = 32; m >= 1; m >>= 1) sb += __shfl_xor(sb, m);
    float pb = expf(lb[s][ws->within[n]] - mb) / sb;

    if (lane == 0) out[n] = pt * pb;
  }
}

extern "C" void kernel_launch(void* const* d_in, const int* in_sizes, int n_in,
                              void* d_out, int out_size, void* d_ws, size_t ws_size,
                              hipStream_t stream) {
  const float* x  = (const float*)d_in[0];
  const int* tgt  = (const int*)d_in[1];
  const float* tw = (const float*)d_in[2];
  const float* tb = (const float*)d_in[3];
  const float* bw = (const float*)d_in[4];
  const float* bb = (const float*)d_in[5];
  float* out = (float*)d_out;
  Ws* ws = (Ws*)d_ws;

  prep_kernel<<<1, 256, 0, stream>>>(tgt, ws);
  partial_kernel<<<TOPBLKS + BOTBLKS, 256, 0, stream>>>(x, tw, bw, ws);
  final_kernel<<<NSAMP / 8, 256, 0, stream>>>(tb, bb, ws, out);
}